// Round 5
// baseline (594.431 us; speedup 1.0000x reference)
//
#include <hip/hip_runtime.h>
#include <math.h>

#define NB 32
#define NT 512
#define NC 4233
#define NU 64
#define LABT 129            // 2*NU+1
#define PADV (-3.4028234663852886e38f)   // float32 min (matches jnp.finfo(f32).min)

// ---------------------------------------------------------------------------
// Kernel 0: emission gather (prep folded in).
// oddS[b][t4][l] (float4 over k=0..3): logit[b][4*t4+k][oddcol(l)]
//   where oddcol(l) = extended-label column for j = 2l+1.
// blankS[b][t] = logit[b][t][blank]  (emission for ALL even j and j=128).
// ---------------------------------------------------------------------------
__global__ __launch_bounds__(256)
void ctc_gather_kernel(const float* __restrict__ logit,   // [B][T][C]
                       const int*   __restrict__ label,   // [U][B]
                       const int*   __restrict__ blank_ptr,
                       float4*      __restrict__ oddS,    // [B*128][64]
                       float*       __restrict__ blankS)  // [B][T]
{
    int tid = blockIdx.x * 256 + threadIdx.x;   // 262144 threads
    int l   = tid & 63;
    int bt4 = tid >> 6;        // b*128 + t4
    int b   = bt4 >> 7;
    int t4  = bt4 & 127;
    int blank = blank_ptr[0];

    int raw = label[l * NB + b];
    int ev  = (raw == blank) ? -1 : raw;
    int col = ev % NC;                 // python floor-mod for -1 pad labels
    if (col < 0) col += NC;

    const float* lg = logit + ((size_t)b * NT + (size_t)t4 * 4) * NC;
    float4 o;
    o.x = lg[col];
    o.y = lg[NC + col];
    o.z = lg[2 * NC + col];
    o.w = lg[3 * NC + col];
    oddS[(size_t)bt4 * 64 + l] = o;

    if (l == 0) {
        float4 bl;
        bl.x = lg[blank];
        bl.y = lg[NC + blank];
        bl.z = lg[2 * NC + blank];
        bl.w = lg[3 * NC + blank];
        *(float4*)&blankS[(size_t)b * NT + t4 * 4] = bl;
    }
}

// ---------------------------------------------------------------------------
// Cross-lane shift-by-1 via DPP wave_shr:1 -- pure VALU, no lgkmcnt.
// lane l gets x[l-1]; lane 0 gets `fill`.
// ---------------------------------------------------------------------------
__device__ __forceinline__ float dpp_wave_shr1(float x, float fill) {
    return __int_as_float(__builtin_amdgcn_update_dpp(
        __float_as_int(fill), __float_as_int(x), 0x138 /*wave_shr:1*/,
        0xf, 0xf, false));
}

// ---------------------------------------------------------------------------
// Kernel 1: single-wave DP scan, fully register-resident emissions.
// 64 steps of odd emissions live in 16 float4 regs (double-buffered; next
// block's 16 dwordx4 issued at block top, pinned by sched_barrier so they
// cannot sink).  Blank emission per step via constant-index v_readlane from
// 8 preloaded VGPRs.  Loop body: ZERO loads, only VALU/TRANS + off-chain
// lane-0 ds_writes.  Lane l holds dp[2l], dp[2l+1]; lane 63 also dp[128].
// ---------------------------------------------------------------------------
__global__ __launch_bounds__(64, 1)
void ctc_scan_kernel(const float4* __restrict__ oddS,   // [B*128][64]
                     const float*  __restrict__ blankS, // [B][T]
                     const int*    __restrict__ label,  // [U][B]
                     const int*    __restrict__ blank_ptr,
                     float* __restrict__ out,           // [B][T][LABT] align
                     float* __restrict__ loss_out)      // [B]
{
    __shared__ __align__(16) unsigned long long bpm[NT][4]; // backptr masks
    __shared__ int   wl[NT];
    __shared__ float fdp[132];

    const int b = blockIdx.x;
    const int l = threadIdx.x;
    const int blank = blank_ptr[0];

    // label-derived state
    int raw = label[l * NB + b];
    unsigned long long nbmask = __ballot(raw != blank);
    const int Y = 2 * (int)__popcll(nbmask) + 1;
    int ev  = (raw == blank) ? -1 : raw;
    int pev = __shfl_up(ev, 1);
    if (l == 0) pev = -1;
    const bool cndO = (ev == blank) || (ev == pev);   // cond for odd j=2l+1

    const float4* ep4 = oddS + (size_t)b * 128 * 64;  // [t4][l]
    const float*  bS  = blankS + (size_t)b * NT;

    // preload blank stream: bv_k[lane l] = blank[64k + l]
    float bv0 = bS[l],       bv1 = bS[64 + l],  bv2 = bS[128 + l],
          bv3 = bS[192 + l], bv4 = bS[256 + l], bv5 = bS[320 + l],
          bv6 = bS[384 + l], bv7 = bS[448 + l];

    // prologue: block 0's odd emissions into bufA
    float4 bufA[16], bufB[16];
#pragma unroll
    for (int q = 0; q < 16; ++q) bufA[q] = ep4[q * 64 + l];
    __builtin_amdgcn_sched_barrier(0);

    // t = 0 init: dp0[0] = blank[0], dp0[1] = odd[0][lane0], else PAD
    float v0 = (l == 0) ? bv0 : PADV;        // dp[2l]
    float v1 = (l == 0) ? bufA[0].x : PADV;  // dp[2l+1]
    float v2 = PADV;                         // dp[128] (lane 63 meaningful)

#define STEP_T(t_, evv, se)                                                    \
    do {                                                                       \
        float u1 = dpp_wave_shr1(v1, PADV);   /* dp[2l-1] */                   \
        /* even j=2l: 2-way lse (bit-exact 1-exp form) */                      \
        float mE   = fmaxf(v0, u1);                                            \
        float lseE = mE + logf(1.0f + expf(-fabsf(v0 - u1)));                  \
        unsigned long long bE = __ballot(v0 < u1);                             \
        /* odd j=2l+1: 3-way lse, exact rounds-0..4 expression */              \
        float c2e = cndO ? PADV : u1;                                          \
        float mO  = fmaxf(fmaxf(v1, v0), c2e);                                 \
        float lseO = mO + logf(expf(v1 - mO) + expf(v0 - mO) + expf(c2e - mO));\
        unsigned long long gAB = __ballot(v1 >= v0);                           \
        unsigned long long gAC = __ballot(v1 >= c2e);                          \
        unsigned long long gBC = __ballot(v0 >= c2e);                          \
        /* j=128: 2-way lse on lane63's (v2, v1) */                            \
        float mL   = fmaxf(v2, v1);                                            \
        float lseL = mL + logf(1.0f + expf(-fabsf(v2 - v1)));                  \
        unsigned long long bL = __ballot(v2 < v1);                             \
        v0 = (se) + lseE;                                                      \
        v1 = (evv) + lseO;                                                     \
        v2 = (se) + lseL;                                                      \
        if (l == 0) {                                                          \
            unsigned long long t0m = gAB & gAC;                                \
            ulonglong2 w01, w23;                                               \
            w01.x = bE;          w01.y = ~t0m & gBC;                           \
            w23.x = ~t0m & ~gBC; w23.y = (bL >> 63);                           \
            *(ulonglong2*)&bpm[t_][0] = w01;                                   \
            *(ulonglong2*)&bpm[t_][2] = w23;                                   \
        }                                                                      \
    } while (0)

// 64 fully-unrolled steps; CUR = this block's 16 float4 regs, NXT prefetched.
#define BLOCK64(base, CUR, NXT, BV, DO_PREFETCH)                               \
    do {                                                                       \
        if (DO_PREFETCH) {                                                     \
            _Pragma("unroll")                                                  \
            for (int q = 0; q < 16; ++q)                                       \
                NXT[q] = ep4[(((base) >> 2) + 16 + q) * 64 + l];               \
            __builtin_amdgcn_sched_barrier(0);                                 \
        }                                                                      \
        _Pragma("unroll")                                                      \
        for (int i = ((base) == 0 ? 1 : 0); i < 64; ++i) {                     \
            float4 cc = CUR[i >> 2];                                           \
            float evv = ((i & 3) == 0) ? cc.x : ((i & 3) == 1) ? cc.y          \
                      : ((i & 3) == 2) ? cc.z : cc.w;                          \
            float se = __int_as_float(__builtin_amdgcn_readlane(               \
                __float_as_int(BV), i));                                       \
            STEP_T((base) + i, evv, se);                                       \
        }                                                                      \
    } while (0)

    BLOCK64(0,   bufA, bufB, bv0, 1);
    BLOCK64(64,  bufB, bufA, bv1, 1);
    BLOCK64(128, bufA, bufB, bv2, 1);
    BLOCK64(192, bufB, bufA, bv3, 1);
    BLOCK64(256, bufA, bufB, bv4, 1);
    BLOCK64(320, bufB, bufA, bv5, 1);
    BLOCK64(384, bufA, bufB, bv6, 1);
    BLOCK64(448, bufB, bufA, bv7, 0);
#undef BLOCK64
#undef STEP_T

    // publish final dp row
    fdp[2 * l]     = v0;
    fdp[2 * l + 1] = v1;
    if (l == 63) fdp[128] = v2;
    __syncthreads();

    // zero-fill align output (overlaps with lane0 backtrack drain)
    float* outA = out + (size_t)b * (NT * LABT);
    {
        float4 z4; z4.x = 0.f; z4.y = 0.f; z4.z = 0.f; z4.w = 0.f;
        float4* o4 = (float4*)outA;
        for (int p = l; p < (NT * LABT) / 4; p += 64) o4[p] = z4;
    }

    // loss + register-ring Viterbi backtrack (lane 0)
    if (l == 0) {
        int i2 = Y - 2; if (i2 < 0) i2 += LABT;   // python wrap for yl==1
        float d1 = fdp[Y - 1];
        float d2 = fdp[i2];
        float mm = fmaxf(d1, d2);
        float la = mm + logf(expf(d1 - mm) + expf(d2 - mm));
        loss_out[b] = -la * 2.0f / (float)(Y - 1);

        int w = (d1 > d2) ? (Y - 1) : i2;
        const ulonglong2* bp2 = (const ulonglong2*)&bpm[0][0];  // 2 per row

#define BLOAD(qa, qb, row) do { qa = bp2[2 * (row)]; qb = bp2[2 * (row) + 1]; } while (0)
#define BPROC(qa, qb, row) do {                                                \
        wl[row] = w;                                                           \
        int lw_ = w >> 1;                                                      \
        int dE_ = (w == 128) ? (int)qb.y : (int)((qa.x >> lw_) & 1ULL);        \
        int dO_ = (int)((qa.y >> lw_) & 1ULL) + 2 * (int)((qb.x >> lw_) & 1ULL);\
        w -= (w & 1) ? dO_ : dE_;                                              \
    } while (0)

        ulonglong2 a0, b0, a1, b1, a2, b2, a3, b3;
        BLOAD(a0, b0, NT - 1);
        BLOAD(a1, b1, NT - 2);
        BLOAD(a2, b2, NT - 3);
        BLOAD(a3, b3, NT - 4);
        int tt;
        for (tt = NT - 1; tt >= 8; tt -= 4) {
            BPROC(a0, b0, tt    ); BLOAD(a0, b0, tt - 4);
            BPROC(a1, b1, tt - 1); BLOAD(a1, b1, tt - 5);
            BPROC(a2, b2, tt - 2); BLOAD(a2, b2, tt - 6);
            BPROC(a3, b3, tt - 3); BLOAD(a3, b3, tt - 7);
        }
        // slots now hold rows 7,6,5,4
        BPROC(a0, b0, 7); BLOAD(a0, b0, 3);
        BPROC(a1, b1, 6); BLOAD(a1, b1, 2);
        BPROC(a2, b2, 5); BLOAD(a2, b2, 1);
        BPROC(a3, b3, 4);
        BPROC(a0, b0, 3);
        BPROC(a1, b1, 2);
        BPROC(a2, b2, 1);
        wl[0] = w;   // bp at t=0 is identity
#undef BLOAD
#undef BPROC
    }
    __syncthreads();   // drain zero stores + publish wl

    // scatter the ones
    for (int t2 = l; t2 < NT; t2 += 64)
        outA[(size_t)t2 * LABT + wl[t2]] = 1.0f;
}

// ---------------------------------------------------------------------------
extern "C" void kernel_launch(void* const* d_in, const int* in_sizes, int n_in,
                              void* d_out, int out_size, void* d_ws, size_t ws_size,
                              hipStream_t stream)
{
    const float* logit = (const float*)d_in[0];
    const int*   label = (const int*)d_in[1];
    const int*   blank = (const int*)d_in[2];

    float* out = (float*)d_out;   // [B*T*LABT] align (0/1 float) then [B] loss

    float4* oddS   = (float4*)d_ws;                        // 4.19 MB
    float*  blankS = (float*)((char*)d_ws + (size_t)NB * 128 * 64 * 16); // 64 KB

    ctc_gather_kernel<<<(NB * 128 * 64) / 256, 256, 0, stream>>>(
        logit, label, blank, oddS, blankS);
    ctc_scan_kernel<<<NB, 64, 0, stream>>>(
        oddS, blankS, label, blank, out, out + (size_t)NB * NT * LABT);
}

// Round 6
// 584.977 us; speedup vs baseline: 1.0162x; 1.0162x over previous
//
#include <hip/hip_runtime.h>
#include <math.h>

#define NB 32
#define NT 512
#define NC 4233
#define NU 64
#define LABT 129            // 2*NU+1
#define PADV (-3.4028234663852886e38f)   // float32 min (matches jnp.finfo(f32).min)

typedef float f32x4 __attribute__((ext_vector_type(4)));

// ---------------------------------------------------------------------------
// Kernel 0: emission gather (prep folded in).  UNCHANGED from round 5 (verified).
// oddS[b][t4][l] (float4 over k=0..3): logit[b][4*t4+k][oddcol(l)]
// blankS[b][t] = logit[b][t][blank]  (emission for ALL even j and j=128).
// ---------------------------------------------------------------------------
__global__ __launch_bounds__(256)
void ctc_gather_kernel(const float* __restrict__ logit,   // [B][T][C]
                       const int*   __restrict__ label,   // [U][B]
                       const int*   __restrict__ blank_ptr,
                       float4*      __restrict__ oddS,    // [B*128][64]
                       float*       __restrict__ blankS)  // [B][T]
{
    int tid = blockIdx.x * 256 + threadIdx.x;   // 262144 threads
    int l   = tid & 63;
    int bt4 = tid >> 6;        // b*128 + t4
    int b   = bt4 >> 7;
    int t4  = bt4 & 127;
    int blank = blank_ptr[0];

    int raw = label[l * NB + b];
    int ev  = (raw == blank) ? -1 : raw;
    int col = ev % NC;                 // python floor-mod for -1 pad labels
    if (col < 0) col += NC;

    const float* lg = logit + ((size_t)b * NT + (size_t)t4 * 4) * NC;
    float4 o;
    o.x = lg[col];
    o.y = lg[NC + col];
    o.z = lg[2 * NC + col];
    o.w = lg[3 * NC + col];
    oddS[(size_t)bt4 * 64 + l] = o;

    if (l == 0) {
        float4 bl;
        bl.x = lg[blank];
        bl.y = lg[NC + blank];
        bl.z = lg[2 * NC + blank];
        bl.w = lg[3 * NC + blank];
        *(float4*)&blankS[(size_t)b * NT + t4 * 4] = bl;
    }
}

// ---------------------------------------------------------------------------
// Cross-lane shift-by-1 via DPP wave_shr:1 -- pure VALU, no lgkmcnt.
// ---------------------------------------------------------------------------
__device__ __forceinline__ float dpp_wave_shr1(float x, float fill) {
    return __int_as_float(__builtin_amdgcn_update_dpp(
        __float_as_int(fill), __float_as_int(x), 0x138 /*wave_shr:1*/,
        0xf, 0xf, false));
}

// ---------------------------------------------------------------------------
// Kernel 1: single-wave DP scan; emissions double-buffered in registers via
// VOLATILE inline-asm global_load_dwordx4 (un-sinkable, unlike r5's plain
// loads which the scheduler sank to their uses -> per-step latency).
// One asm s_waitcnt vmcnt(0) per 64-step block.  Loop body: zero loads.
// Lane l holds dp[2l], dp[2l+1]; lane 63 also dp[128].
// ---------------------------------------------------------------------------
__global__ __launch_bounds__(64, 1)
void ctc_scan_kernel(const float4* __restrict__ oddS,   // [B*128][64]
                     const float*  __restrict__ blankS, // [B][T]
                     const int*    __restrict__ label,  // [U][B]
                     const int*    __restrict__ blank_ptr,
                     float* __restrict__ out,           // [B][T][LABT] align
                     float* __restrict__ loss_out)      // [B]
{
    __shared__ __align__(16) unsigned long long bpm[NT][4]; // backptr masks
    __shared__ int   wl[NT];
    __shared__ float fdp[132];

    const int b = blockIdx.x;
    const int l = threadIdx.x;
    const int blank = blank_ptr[0];

    // label-derived state
    int raw = label[l * NB + b];
    unsigned long long nbmask = __ballot(raw != blank);
    const int Y = 2 * (int)__popcll(nbmask) + 1;
    int ev  = (raw == blank) ? -1 : raw;
    int pev = __shfl_up(ev, 1);
    if (l == 0) pev = -1;
    const bool cndO = (ev == blank) || (ev == pev);   // cond for odd j=2l+1

    const char*  epb = (const char*)(oddS + (size_t)b * 128 * 64);  // [t4][l]
    const float* bS  = blankS + (size_t)b * NT;

    // blank stream: bv_k[lane l] = blank[64k + l]  (pinned by first WAITVM0)
    float bv0 = bS[l],       bv1 = bS[64 + l],  bv2 = bS[128 + l],
          bv3 = bS[192 + l], bv4 = bS[256 + l], bv5 = bS[320 + l],
          bv6 = bS[384 + l], bv7 = bS[448 + l];

#define ASM_LD(dst, addr, imm)                                                 \
    asm volatile("global_load_dwordx4 %0, %1, off offset:" #imm                \
                 : "=v"(dst) : "v"(addr))

// load block nb (16 t4-rows) into 16 f32x4 regs; volatile -> cannot sink
#define PREFETCH(NXT, nb)                                                      \
    do {                                                                       \
        const char* g0_ = epb + (((nb) * 16 + 0)  * 64 + l) * 16;              \
        const char* g1_ = epb + (((nb) * 16 + 4)  * 64 + l) * 16;              \
        const char* g2_ = epb + (((nb) * 16 + 8)  * 64 + l) * 16;              \
        const char* g3_ = epb + (((nb) * 16 + 12) * 64 + l) * 16;              \
        ASM_LD(NXT[0],  g0_, 0);    ASM_LD(NXT[1],  g0_, 1024);                \
        ASM_LD(NXT[2],  g0_, 2048); ASM_LD(NXT[3],  g0_, 3072);                \
        ASM_LD(NXT[4],  g1_, 0);    ASM_LD(NXT[5],  g1_, 1024);                \
        ASM_LD(NXT[6],  g1_, 2048); ASM_LD(NXT[7],  g1_, 3072);                \
        ASM_LD(NXT[8],  g2_, 0);    ASM_LD(NXT[9],  g2_, 1024);                \
        ASM_LD(NXT[10], g2_, 2048); ASM_LD(NXT[11], g2_, 3072);                \
        ASM_LD(NXT[12], g3_, 0);    ASM_LD(NXT[13], g3_, 1024);                \
        ASM_LD(NXT[14], g3_, 2048); ASM_LD(NXT[15], g3_, 3072);                \
        __builtin_amdgcn_sched_barrier(0);                                     \
    } while (0)

#define WAITVM0                                                                \
    do { asm volatile("s_waitcnt vmcnt(0)" ::: "memory");                      \
         __builtin_amdgcn_sched_barrier(0); } while (0)

    f32x4 bufA[16], bufB[16];
    PREFETCH(bufA, 0);
    WAITVM0;                 // bufA + bv* resident

    // t = 0 init: dp0[0] = blank[0], dp0[1] = odd[0][lane0], else PAD
    float v0 = (l == 0) ? bv0 : PADV;         // dp[2l]
    float v1 = (l == 0) ? bufA[0][0] : PADV;  // dp[2l+1]
    float v2 = PADV;                          // dp[128] (lane 63 meaningful)

#define STEP_T(t_, evv, se)                                                    \
    do {                                                                       \
        float u1 = dpp_wave_shr1(v1, PADV);   /* dp[2l-1] */                   \
        /* even j=2l: 2-way lse (bit-exact 1-exp form) */                      \
        float mE   = fmaxf(v0, u1);                                            \
        float lseE = mE + logf(1.0f + expf(-fabsf(v0 - u1)));                  \
        unsigned long long bE = __ballot(v0 < u1);                             \
        /* odd j=2l+1: 3-way lse, exact rounds-0..5 expression */              \
        float c2e = cndO ? PADV : u1;                                          \
        float mO  = fmaxf(fmaxf(v1, v0), c2e);                                 \
        float lseO = mO + logf(expf(v1 - mO) + expf(v0 - mO) + expf(c2e - mO));\
        unsigned long long gAB = __ballot(v1 >= v0);                           \
        unsigned long long gAC = __ballot(v1 >= c2e);                          \
        unsigned long long gBC = __ballot(v0 >= c2e);                          \
        /* j=128: 2-way lse on lane63's (v2, v1) */                            \
        float mL   = fmaxf(v2, v1);                                            \
        float lseL = mL + logf(1.0f + expf(-fabsf(v2 - v1)));                  \
        unsigned long long bL = __ballot(v2 < v1);                             \
        v0 = (se) + lseE;                                                      \
        v1 = (evv) + lseO;                                                     \
        v2 = (se) + lseL;                                                      \
        if (l == 0) {                                                          \
            unsigned long long t0m = gAB & gAC;                                \
            ulonglong2 w01, w23;                                               \
            w01.x = bE;          w01.y = ~t0m & gBC;                           \
            w23.x = ~t0m & ~gBC; w23.y = (bL >> 63);                           \
            *(ulonglong2*)&bpm[t_][0] = w01;                                   \
            *(ulonglong2*)&bpm[t_][2] = w23;                                   \
        }                                                                      \
    } while (0)

// 64 fully-unrolled steps; prefetch next block first (volatile, pinned at
// top), compute current block, then ONE waitcnt for the in-flight block.
#define BLOCK64(base, CUR, NXT, BV, PF, WT)                                    \
    do {                                                                       \
        if (PF) PREFETCH(NXT, ((base) >> 6) + 1);                              \
        _Pragma("unroll")                                                      \
        for (int i = ((base) == 0 ? 1 : 0); i < 64; ++i) {                     \
            f32x4 cc = CUR[i >> 2];                                            \
            float evv = ((i & 3) == 0) ? cc[0] : ((i & 3) == 1) ? cc[1]        \
                      : ((i & 3) == 2) ? cc[2] : cc[3];                        \
            float se = __int_as_float(__builtin_amdgcn_readlane(               \
                __float_as_int(BV), i));                                       \
            STEP_T((base) + i, evv, se);                                       \
        }                                                                      \
        if (WT) WAITVM0;                                                       \
    } while (0)

    BLOCK64(0,   bufA, bufB, bv0, 1, 1);
    BLOCK64(64,  bufB, bufA, bv1, 1, 1);
    BLOCK64(128, bufA, bufB, bv2, 1, 1);
    BLOCK64(192, bufB, bufA, bv3, 1, 1);
    BLOCK64(256, bufA, bufB, bv4, 1, 1);
    BLOCK64(320, bufB, bufA, bv5, 1, 1);
    BLOCK64(384, bufA, bufB, bv6, 1, 1);
    BLOCK64(448, bufB, bufA, bv7, 0, 0);
#undef BLOCK64
#undef STEP_T

    // publish final dp row
    fdp[2 * l]     = v0;
    fdp[2 * l + 1] = v1;
    if (l == 63) fdp[128] = v2;
    __syncthreads();

    // zero-fill align output (overlaps with lane0 backtrack drain)
    float* outA = out + (size_t)b * (NT * LABT);
    {
        float4 z4; z4.x = 0.f; z4.y = 0.f; z4.z = 0.f; z4.w = 0.f;
        float4* o4 = (float4*)outA;
        for (int p = l; p < (NT * LABT) / 4; p += 64) o4[p] = z4;
    }

    // loss + register-ring Viterbi backtrack (lane 0)
    if (l == 0) {
        int i2 = Y - 2; if (i2 < 0) i2 += LABT;   // python wrap for yl==1
        float d1 = fdp[Y - 1];
        float d2 = fdp[i2];
        float mm = fmaxf(d1, d2);
        float la = mm + logf(expf(d1 - mm) + expf(d2 - mm));
        loss_out[b] = -la * 2.0f / (float)(Y - 1);

        int w = (d1 > d2) ? (Y - 1) : i2;
        const ulonglong2* bp2 = (const ulonglong2*)&bpm[0][0];  // 2 per row

#define BLOAD(qa, qb, row) do { qa = bp2[2 * (row)]; qb = bp2[2 * (row) + 1]; } while (0)
#define BPROC(qa, qb, row) do {                                                \
        wl[row] = w;                                                           \
        int lw_ = w >> 1;                                                      \
        int dE_ = (w == 128) ? (int)qb.y : (int)((qa.x >> lw_) & 1ULL);        \
        int dO_ = (int)((qa.y >> lw_) & 1ULL) + 2 * (int)((qb.x >> lw_) & 1ULL);\
        w -= (w & 1) ? dO_ : dE_;                                              \
    } while (0)

        ulonglong2 a0, b0, a1, b1, a2, b2, a3, b3;
        BLOAD(a0, b0, NT - 1);
        BLOAD(a1, b1, NT - 2);
        BLOAD(a2, b2, NT - 3);
        BLOAD(a3, b3, NT - 4);
        int tt;
        for (tt = NT - 1; tt >= 8; tt -= 4) {
            BPROC(a0, b0, tt    ); BLOAD(a0, b0, tt - 4);
            BPROC(a1, b1, tt - 1); BLOAD(a1, b1, tt - 5);
            BPROC(a2, b2, tt - 2); BLOAD(a2, b2, tt - 6);
            BPROC(a3, b3, tt - 3); BLOAD(a3, b3, tt - 7);
        }
        // slots now hold rows 7,6,5,4
        BPROC(a0, b0, 7); BLOAD(a0, b0, 3);
        BPROC(a1, b1, 6); BLOAD(a1, b1, 2);
        BPROC(a2, b2, 5); BLOAD(a2, b2, 1);
        BPROC(a3, b3, 4);
        BPROC(a0, b0, 3);
        BPROC(a1, b1, 2);
        BPROC(a2, b2, 1);
        wl[0] = w;   // bp at t=0 is identity
#undef BLOAD
#undef BPROC
    }
    __syncthreads();   // drain zero stores + publish wl

    // scatter the ones
    for (int t2 = l; t2 < NT; t2 += 64)
        outA[(size_t)t2 * LABT + wl[t2]] = 1.0f;
}

// ---------------------------------------------------------------------------
extern "C" void kernel_launch(void* const* d_in, const int* in_sizes, int n_in,
                              void* d_out, int out_size, void* d_ws, size_t ws_size,
                              hipStream_t stream)
{
    const float* logit = (const float*)d_in[0];
    const int*   label = (const int*)d_in[1];
    const int*   blank = (const int*)d_in[2];

    float* out = (float*)d_out;   // [B*T*LABT] align (0/1 float) then [B] loss

    float4* oddS   = (float4*)d_ws;                        // 4.19 MB
    float*  blankS = (float*)((char*)d_ws + (size_t)NB * 128 * 64 * 16); // 64 KB

    ctc_gather_kernel<<<(NB * 128 * 64) / 256, 256, 0, stream>>>(
        logit, label, blank, oddS, blankS);
    ctc_scan_kernel<<<NB, 64, 0, stream>>>(
        oddS, blankS, label, blank, out, out + (size_t)NB * NT * LABT);
}